// Round 10
// baseline (289.537 us; speedup 1.0000x reference)
//
#include <hip/hip_runtime.h>
#include <cstdint>

// ---------------------------------------------------------------------------
// out = relu((softmax((Y W^T)(Y W^T)^T) @ Y) @ (-0.5(Wf+Wf^T)) + B)
// n=4096, d=1024, fp32 in/out.
// R10 (= R9 resubmit; R9 hit GPUAcquisitionTimeout, never ran):
// GEMM2 K-loop simplified to depth-1 prefetch + ONE barrier per K-tile
// (vmcnt(0) pre-landed ~8000cyc -> cheap; stage(t+1) targets the other
// buffer so no mid-tile read-certification barrier needed). Body is
// compiler-scheduled: B-frags then per-m-octant {2 ds_read, 12 MFMA}.
// Everything else verbatim from R8 (passed, absmax 0.015625).
// ---------------------------------------------------------------------------

typedef __attribute__((ext_vector_type(8))) short short8;
typedef __attribute__((ext_vector_type(4))) short short4v;
typedef __attribute__((ext_vector_type(4))) float f32x4;

__device__ __forceinline__ short f2bf(float x) {            // RNE fp32 -> bf16
    unsigned u = __builtin_bit_cast(unsigned, x);
    u += 0x7fffu + ((u >> 16) & 1u);
    return (short)(u >> 16);
}
__device__ __forceinline__ float bf2f(short s) {
    unsigned u = ((unsigned)(unsigned short)s) << 16;
    return __builtin_bit_cast(float, u);
}

typedef const __attribute__((address_space(1))) void* gas1_t;
typedef __attribute__((address_space(3))) void* las3_t;
__device__ __forceinline__ void cp16(const void* g, void* l) {
    __builtin_amdgcn_global_load_lds((gas1_t)(uintptr_t)g, (las3_t)(uintptr_t)l, 16, 0, 0);
}

#define MFMA16(A, B, C) __builtin_amdgcn_mfma_f32_16x16x32_bf16(A, B, C, 0, 0, 0)

// ---------------------------------------------------------------------------
// GEMM2: 256x256 tile, split-3 bf16. C[M,N] = (Ah+Al)[M,K] @ (Bh+Bl)^T.
// 512 thr / 8 waves (2Mx4N), wave tile 128x64, acc[8][4]. BK=32.
// LDS: 2 bufs x (Ah|Al|Bh|Bl planes of [256][32]sh) = 128 KB. 1 block/CU.
// Per K-tile: vmcnt(0) [pre-landed] -> barrier -> stage(t+1, other buf) ->
//   B-frag reads -> per-m-octant {A-pair read, 12 MFMA} (compiler-pipelined).
// ---------------------------------------------------------------------------
__global__ __launch_bounds__(512, 1)
void gemm256_split(const short* __restrict__ Ah, const short* __restrict__ Al,
                   const short* __restrict__ Bh, const short* __restrict__ Bl,
                   short* __restrict__ Ch, short* __restrict__ Cl,
                   int M, int N, int K)
{
    __shared__ short lds[2][32768];           // 128 KB

    const int tid  = threadIdx.x;
    const int lane = tid & 63;
    const int wave = tid >> 6;
    const int wr   = wave >> 2;               // 0..1  (128-row half)
    const int wc   = wave & 3;                // 0..3  (64-col quarter)

    const int gx  = gridDim.x;
    const int nwg = gx * gridDim.y;
    int lin = blockIdx.y * gx + blockIdx.x;
    if ((nwg & 7) == 0) { const int cpx = nwg >> 3; lin = (lin & 7) * cpx + (lin >> 3); }
    const int bm = (lin / gx) << 8;
    const int bn = (lin % gx) << 8;

    f32x4 acc[8][4];
#pragma unroll
    for (int m = 0; m < 8; ++m)
#pragma unroll
        for (int n = 0; n < 4; ++n)
#pragma unroll
            for (int q = 0; q < 4; ++q) acc[m][n][q] = 0.f;

    // staging: per plane-half (128 rows x 32), thread -> one 16B slot (R4 map)
    const int srow = tid >> 2;                               // 0..127
    const int csw  = (tid & 3) ^ ((tid >> 3) & 3);           // logical chunk
    const size_t oA = (size_t)(bm + srow) * K + csw * 8;
    const size_t oB = (size_t)(bn + srow) * K + csw * 8;
    const short* s0 = Ah + oA; const short* s1 = Al + oA;
    const short* s2 = Bh + oB; const short* s3 = Bl + oB;
    const size_t h128 = (size_t)128 * K;

    auto stage = [&](int t) {                  // 8 cp16 / thread / K-tile
        short* db = &lds[t & 1][0] + tid * 8;
        const int ko = t * 32;
        cp16(s0 + ko, db);          cp16(s0 + h128 + ko, db + 4096);
        cp16(s1 + ko, db + 8192);   cp16(s1 + h128 + ko, db + 12288);
        cp16(s2 + ko, db + 16384);  cp16(s2 + h128 + ko, db + 20480);
        cp16(s3 + ko, db + 24576);  cp16(s3 + h128 + ko, db + 28672);
    };

    // read-side (R3/R4-verified swizzle; row alignment mod 16 preserved)
    const int swz  = ((lane >> 4) ^ ((lane >> 1) & 3)) * 8;
    const int aoff = (wr * 128 + (lane & 15)) * 32 + swz;
    const int boff = (wc * 64  + (lane & 15)) * 32 + swz;

    const int nt = K >> 5;                    // 32 for K=1024
    stage(0);

    for (int t = 0; t < nt; ++t) {
        // stage(t) was issued one full tile (~8000 cyc) ago: vmcnt(0) is a
        // cheap certification, and since EVERY wave drains before the
        // barrier, the barrier collectively certifies buf[t] is complete.
        asm volatile("s_waitcnt vmcnt(0)" ::: "memory");
        __builtin_amdgcn_s_barrier();
        __builtin_amdgcn_sched_barrier(0);

        if (t + 1 < nt) stage(t + 1);          // other buffer: no read hazard

        const short* base = &lds[t & 1][0];
        short8 fbh[4], fbl[4];
#pragma unroll
        for (int n = 0; n < 4; ++n) {
            fbh[n] = *(const short8*)(base + 16384 + boff + n * 512);
            fbl[n] = *(const short8*)(base + 24576 + boff + n * 512);
        }
        __builtin_amdgcn_s_setprio(1);
#pragma unroll
        for (int m = 0; m < 8; ++m) {
            const short8 fah = *(const short8*)(base + aoff + m * 512);
            const short8 fal = *(const short8*)(base + 8192 + aoff + m * 512);
#pragma unroll
            for (int n = 0; n < 4; ++n) {
                acc[m][n] = MFMA16(fah, fbh[n], acc[m][n]);
                acc[m][n] = MFMA16(fah, fbl[n], acc[m][n]);
                acc[m][n] = MFMA16(fal, fbh[n], acc[m][n]);
            }
        }
        __builtin_amdgcn_s_setprio(0);
    }

    // epilogue: split write. C/D: col = lane&15, row = (lane>>4)*4 + q
    const int crow0 = bm + wr * 128 + ((lane >> 4) << 2);
    const int ccol0 = bn + wc * 64 + (lane & 15);
#pragma unroll
    for (int n = 0; n < 4; ++n) {
        const int c = ccol0 + n * 16;
#pragma unroll
        for (int m = 0; m < 8; ++m)
#pragma unroll
            for (int q = 0; q < 4; ++q) {
                const int r = crow0 + m * 16 + q;
                const float v = acc[m][n][q];
                const short hh = f2bf(v);
                Ch[(size_t)r * N + c] = hh;
                Cl[(size_t)r * N + c] = f2bf(v - bf2f(hh));
            }
    }
}

// ---------------------------------------------------------------------------
// 128x128 phase template (GEMM1/3/4) — verbatim from R8 (passed).
// OUTMODE: 0 split bf16, 1 hi bf16, 2 f32+bias+relu.
// ---------------------------------------------------------------------------
template<bool SPLIT, int OUTMODE>
__global__ __launch_bounds__(512, 2)
void gemm128_phase(const short* __restrict__ Ah, const short* __restrict__ Al,
                   const short* __restrict__ Bh, const short* __restrict__ Bl,
                   const float* __restrict__ bias, void* Co_, void* Cl_,
                   int M, int N, int K)
{
    constexpr int BK = SPLIT ? 32 : 64;
    __shared__ short lds[2][16384];           // 64 KB

    const int tid  = threadIdx.x;
    const int lane = tid & 63;
    const int wave = tid >> 6;
    const int wr   = wave >> 2;               // 0..1
    const int wc   = wave & 3;                // 0..3

    const int gx  = gridDim.x;
    const int nwg = gx * gridDim.y;
    int lin = blockIdx.y * gx + blockIdx.x;
    if ((nwg & 7) == 0) { const int cpx = nwg >> 3; lin = (lin & 7) * cpx + (lin >> 3); }
    const int bm = (lin / gx) << 7;
    const int bn = (lin % gx) << 7;

    f32x4 acc[4][2];
#pragma unroll
    for (int m = 0; m < 4; ++m)
#pragma unroll
        for (int n = 0; n < 2; ++n)
#pragma unroll
            for (int q = 0; q < 4; ++q) acc[m][n][q] = 0.f;

    // staging sources: 4 cp16/thread/K-tile (R4-verified maps)
    const short *p0, *p1, *p2, *p3;
    if constexpr (SPLIT) {
        const int row = tid >> 2;                        // 0..127
        const int c4  = (tid & 3) ^ ((tid >> 3) & 3);
        const size_t oA = (size_t)(bm + row) * K + c4 * 8;
        const size_t oB = (size_t)(bn + row) * K + c4 * 8;
        p0 = Ah + oA; p1 = Al + oA; p2 = Bh + oB; p3 = Bl + oB;
    } else {
        const int row = tid >> 3;                        // 0..63
        const int lch = (tid & 7) ^ ((tid >> 3) & 7);
        const size_t oA = (size_t)(bm + row) * K + lch * 8;
        const size_t oB = (size_t)(bn + row) * K + lch * 8;
        p0 = Ah + oA; p1 = p0 + (size_t)64 * K;
        p2 = Bh + oB; p3 = p2 + (size_t)64 * K;
    }

    auto stage = [&](int t) {
        short* db = &lds[t & 1][0] + tid * 8;
        const int ko = t * BK;
        cp16(p0 + ko, db);
        cp16(p1 + ko, db + 4096);
        cp16(p2 + ko, db + 8192);
        cp16(p3 + ko, db + 12288);
    };

    int aoff, boff;
    if constexpr (SPLIT) {
        const int swz = ((lane >> 4) ^ ((lane >> 1) & 3)) * 8;
        aoff = (wr * 64 + (lane & 15)) * 32 + swz;
        boff = (wc * 32 + (lane & 15)) * 32 + swz;
    } else {
        aoff = (wr * 64 + (lane & 15)) * 64;
        boff = (wc * 32 + (lane & 15)) * 64;
    }

    const int nt = K / BK;
    stage(0); stage(1);

    for (int t = 0; t < nt; ++t) {
        if (t < nt - 1) { asm volatile("s_waitcnt vmcnt(4)" ::: "memory"); }
        else            { asm volatile("s_waitcnt vmcnt(0)" ::: "memory"); }
        __builtin_amdgcn_s_barrier();
        __builtin_amdgcn_sched_barrier(0);

        const short* base = &lds[t & 1][0];
        if constexpr (SPLIT) {
            short8 fah[4], fal[4], fbh[2], fbl[2];
#pragma unroll
            for (int n = 0; n < 2; ++n) {
                fbh[n] = *(const short8*)(base + 8192  + boff + n * 512);
                fbl[n] = *(const short8*)(base + 12288 + boff + n * 512);
            }
#pragma unroll
            for (int m = 0; m < 4; ++m) {
                fah[m] = *(const short8*)(base + aoff + m * 512);
                fal[m] = *(const short8*)(base + 4096 + aoff + m * 512);
            }
            __builtin_amdgcn_s_setprio(1);
#pragma unroll
            for (int m = 0; m < 2; ++m)
#pragma unroll
                for (int n = 0; n < 2; ++n) {
                    acc[m][n] = MFMA16(fah[m], fbh[n], acc[m][n]);
                    acc[m][n] = MFMA16(fah[m], fbl[n], acc[m][n]);
                    acc[m][n] = MFMA16(fal[m], fbh[n], acc[m][n]);
                }
            __builtin_amdgcn_s_setprio(0);
            asm volatile("s_waitcnt lgkmcnt(0)" ::: "memory");
            __builtin_amdgcn_sched_barrier(0);
            __builtin_amdgcn_s_barrier();
            __builtin_amdgcn_sched_barrier(0);
            if (t + 2 < nt) stage(t + 2);
            __builtin_amdgcn_s_setprio(1);
#pragma unroll
            for (int m = 2; m < 4; ++m)
#pragma unroll
                for (int n = 0; n < 2; ++n) {
                    acc[m][n] = MFMA16(fah[m], fbh[n], acc[m][n]);
                    acc[m][n] = MFMA16(fah[m], fbl[n], acc[m][n]);
                    acc[m][n] = MFMA16(fal[m], fbh[n], acc[m][n]);
                }
            __builtin_amdgcn_s_setprio(0);
        } else {
            short8 fa[2][4], fb[2][2];
#pragma unroll
            for (int ks = 0; ks < 2; ++ks) {
                const int sw = ((ks * 4 + (lane >> 4)) ^ (lane & 7)) * 8;
#pragma unroll
                for (int m = 0; m < 4; ++m)
                    fa[ks][m] = *(const short8*)(base + aoff + sw + m * 1024);
#pragma unroll
                for (int n = 0; n < 2; ++n)
                    fb[ks][n] = *(const short8*)(base + 8192 + boff + sw + n * 1024);
            }
            __builtin_amdgcn_s_setprio(1);
#pragma unroll
            for (int m = 0; m < 4; ++m)
#pragma unroll
                for (int n = 0; n < 2; ++n)
                    acc[m][n] = MFMA16(fa[0][m], fb[0][n], acc[m][n]);
            __builtin_amdgcn_s_setprio(0);
            asm volatile("s_waitcnt lgkmcnt(0)" ::: "memory");
            __builtin_amdgcn_sched_barrier(0);
            __builtin_amdgcn_s_barrier();
            __builtin_amdgcn_sched_barrier(0);
            if (t + 2 < nt) stage(t + 2);
            __builtin_amdgcn_s_setprio(1);
#pragma unroll
            for (int m = 0; m < 4; ++m)
#pragma unroll
                for (int n = 0; n < 2; ++n)
                    acc[m][n] = MFMA16(fa[1][m], fb[1][n], acc[m][n]);
            __builtin_amdgcn_s_setprio(0);
        }
    }

    // epilogue: C/D layout col = lane&15, row = (lane>>4)*4 + q
    const int crow0 = bm + wr * 64 + ((lane >> 4) << 2);
    const int ccol0 = bn + wc * 32 + (lane & 15);
    if constexpr (OUTMODE == 2) {
        float* C = (float*)Co_;
#pragma unroll
        for (int n = 0; n < 2; ++n) {
            const int c = ccol0 + n * 16;
            const float bv = bias[c];
#pragma unroll
            for (int m = 0; m < 4; ++m)
#pragma unroll
                for (int q = 0; q < 4; ++q) {
                    const int r = crow0 + m * 16 + q;
                    C[(size_t)r * N + c] = fmaxf(acc[m][n][q] + bv, 0.f);
                }
        }
    } else if constexpr (OUTMODE == 1) {
        short* Ch = (short*)Co_;
#pragma unroll
        for (int n = 0; n < 2; ++n) {
            const int c = ccol0 + n * 16;
#pragma unroll
            for (int m = 0; m < 4; ++m)
#pragma unroll
                for (int q = 0; q < 4; ++q) {
                    const int r = crow0 + m * 16 + q;
                    Ch[(size_t)r * N + c] = f2bf(acc[m][n][q]);
                }
        }
    } else {
        short* Ch = (short*)Co_;
        short* Cl = (short*)Cl_;
#pragma unroll
        for (int n = 0; n < 2; ++n) {
            const int c = ccol0 + n * 16;
#pragma unroll
            for (int m = 0; m < 4; ++m)
#pragma unroll
                for (int q = 0; q < 4; ++q) {
                    const int r = crow0 + m * 16 + q;
                    const float v = acc[m][n][q];
                    const short hh = f2bf(v);
                    Ch[(size_t)r * N + c] = hh;
                    Cl[(size_t)r * N + c] = f2bf(v - bf2f(hh));
                }
        }
    }
}

// ---------------------------------------------------------------------------
// Row softmax over split logits; writes PROBABILITIES as hi-bf16 into Shi.
// ---------------------------------------------------------------------------
__global__ __launch_bounds__(256)
void softmax_hi(short* __restrict__ Shi, const short* __restrict__ Slo)
{
    const int row = blockIdx.x;
    short8* ph = (short8*)(Shi + (size_t)row * 4096);
    const short8* pl = (const short8*)(Slo + (size_t)row * 4096);
    const int t = threadIdx.x;

    short8 h0 = ph[t], h1 = ph[t + 256];
    short8 l0 = pl[t], l1 = pl[t + 256];
    float x[16];
#pragma unroll
    for (int j = 0; j < 8; ++j) {
        x[j]     = bf2f(h0[j]) + bf2f(l0[j]);
        x[8 + j] = bf2f(h1[j]) + bf2f(l1[j]);
    }
    float mx = x[0];
#pragma unroll
    for (int j = 1; j < 16; ++j) mx = fmaxf(mx, x[j]);
#pragma unroll
    for (int off = 32; off > 0; off >>= 1) mx = fmaxf(mx, __shfl_xor(mx, off));

    __shared__ float rm[4], rs[4];
    const int wv = t >> 6, ln = t & 63;
    if (ln == 0) rm[wv] = mx;
    __syncthreads();
    mx = fmaxf(fmaxf(rm[0], rm[1]), fmaxf(rm[2], rm[3]));

    float s = 0.f;
#pragma unroll
    for (int j = 0; j < 16; ++j) { x[j] = __expf(x[j] - mx); s += x[j]; }
#pragma unroll
    for (int off = 32; off > 0; off >>= 1) s += __shfl_xor(s, off);
    if (ln == 0) rs[wv] = s;
    __syncthreads();
    s = rs[0] + rs[1] + rs[2] + rs[3];

    const float inv = 1.f / s;
    short8 o0, o1;
#pragma unroll
    for (int j = 0; j < 8; ++j) {
        o0[j] = f2bf(x[j] * inv);
        o1[j] = f2bf(x[8 + j] * inv);
    }
    ph[t] = o0; ph[t + 256] = o1;
}

// ---------------------------------------------------------------------------
// Y (4096x1024 f32) -> Yhi/Ylo (row-major split) + Ythi (transposed hi bf16)
// ---------------------------------------------------------------------------
__global__ __launch_bounds__(256)
void split_y(const float* __restrict__ Y, short* __restrict__ Yhi,
             short* __restrict__ Ylo, short* __restrict__ Yt)
{
    __shared__ float tb[64][65];
    const int rb = blockIdx.y * 64, cb = blockIdx.x * 64;
    const int t = threadIdx.x;
    const int r = t >> 4, c4 = (t & 15) * 4;
#pragma unroll
    for (int it = 0; it < 4; ++it) {
        const int row = rb + r + it * 16;
        const float4 v = *(const float4*)&Y[(size_t)row * 1024 + cb + c4];
        const float f[4] = {v.x, v.y, v.z, v.w};
        short4v h, l;
#pragma unroll
        for (int k = 0; k < 4; ++k) {
            const short hh = f2bf(f[k]);
            h[k] = hh;
            l[k] = f2bf(f[k] - bf2f(hh));
        }
        *(short4v*)&Yhi[(size_t)row * 1024 + cb + c4] = h;
        *(short4v*)&Ylo[(size_t)row * 1024 + cb + c4] = l;
        tb[r + it * 16][c4 + 0] = v.x; tb[r + it * 16][c4 + 1] = v.y;
        tb[r + it * 16][c4 + 2] = v.z; tb[r + it * 16][c4 + 3] = v.w;
    }
    __syncthreads();
    const int orow = t >> 2, oc0 = (t & 3) * 16;
    short8 h8[2];
#pragma unroll
    for (int g = 0; g < 2; ++g)
#pragma unroll
        for (int j = 0; j < 8; ++j)
            h8[g][j] = f2bf(tb[oc0 + g * 8 + j][orow]);
    const size_t ob = (size_t)(cb + orow) * 4096 + rb + oc0;
    *(short8*)&Yt[ob] = h8[0];
    *(short8*)&Yt[ob + 8] = h8[1];
}

// W (1024x1024 f32) -> Whi/Wlo
__global__ __launch_bounds__(256)
void split_w(const float* __restrict__ Wm, short* __restrict__ Wh, short* __restrict__ Wl)
{
    const size_t idx = ((size_t)blockIdx.x * 256 + threadIdx.x) * 4;
    const float4 v = *(const float4*)&Wm[idx];
    const float f[4] = {v.x, v.y, v.z, v.w};
    short4v h, l;
#pragma unroll
    for (int k = 0; k < 4; ++k) {
        const short hh = f2bf(f[k]);
        h[k] = hh;
        l[k] = f2bf(f[k] - bf2f(hh));
    }
    *(short4v*)&Wh[idx] = h;
    *(short4v*)&Wl[idx] = l;
}

// Wfeh = bf16(-0.5*(Wf + Wf^T))
__global__ __launch_bounds__(256)
void symm_hi(const float* __restrict__ Wf, short* __restrict__ Fh)
{
    const int i  = blockIdx.x;
    const int j0 = threadIdx.x * 4;
    const float4 rv = *(const float4*)&Wf[(size_t)i * 1024 + j0];
    const float c0 = Wf[(size_t)(j0 + 0) * 1024 + i];
    const float c1 = Wf[(size_t)(j0 + 1) * 1024 + i];
    const float c2 = Wf[(size_t)(j0 + 2) * 1024 + i];
    const float c3 = Wf[(size_t)(j0 + 3) * 1024 + i];
    short4v h;
    h[0] = f2bf(-0.5f * (rv.x + c0));
    h[1] = f2bf(-0.5f * (rv.y + c1));
    h[2] = f2bf(-0.5f * (rv.z + c2));
    h[3] = f2bf(-0.5f * (rv.w + c3));
    *(short4v*)&Fh[(size_t)i * 1024 + j0] = h;
}

// ---------------------------------------------------------------------------
extern "C" void kernel_launch(void* const* d_in, const int* in_sizes, int n_in,
                              void* d_out, int out_size, void* d_ws, size_t ws_size,
                              hipStream_t stream)
{
    const float* Y  = (const float*)d_in[0];   // (4096, 1024)
    const float* W  = (const float*)d_in[1];   // (1024, 1024)
    const float* Wf = (const float*)d_in[2];   // (1024, 1024)
    const float* Bb = (const float*)d_in[3];   // (1, 1024)
    float* out = (float*)d_out;

    const int n = 4096, d = 1024;

    // ws layout, 94.4 MB (same as R3-R8):
    char* w = (char*)d_ws;
    short* Ythi = (short*)w; w += (size_t)d * n * 2;   //  8.39 MB
    short* Wfeh = (short*)w; w += (size_t)d * d * 2;   //  2.10 MB
    short* YWth = (short*)w; w += (size_t)n * d * 2;   //  8.39 MB (reused as Zhi)
    short* YWtl = (short*)w; w += (size_t)n * d * 2;   //  8.39 MB
    short* Shi  = (short*)w; w += (size_t)n * n * 2;   // 33.55 MB
    short* Slo  = (short*)w; w += (size_t)n * n * 2;   // 33.55 MB
    // transient split inputs aliased into Shi region (dead before S written):
    short* Yhi = Shi;
    short* Ylo = Yhi + (size_t)n * d;
    short* Whi = Ylo + (size_t)n * d;
    short* Wlo = Whi + (size_t)d * d;
    short* Zhi = YWth;                                  // YWt dead after GEMM2

    split_y<<<dim3(16, 64), 256, 0, stream>>>(Y, Yhi, Ylo, Ythi);
    split_w<<<dim3(1024), 256, 0, stream>>>(W, Whi, Wlo);
    symm_hi<<<dim3(1024), 256, 0, stream>>>(Wf, Wfeh);

    // 1) YWt = Y @ W^T (split 3-product, 128^2 phase template)
    gemm128_phase<true, 0><<<dim3(8, 32), 512, 0, stream>>>(
        Yhi, Ylo, Whi, Wlo, nullptr, YWth, YWtl, n, d, d);

    // 2) S = YWt @ YWt^T (split 3-product, 256^2 full grid, single-barrier)
    gemm256_split<<<dim3(16, 16), 512, 0, stream>>>(
        YWth, YWtl, YWth, YWtl, Shi, Slo, n, n, d);

    // 3) A = softmax(S): probabilities as hi-bf16 into Shi
    softmax_hi<<<dim3(n), 256, 0, stream>>>(Shi, Slo);

    // 4) Z = A @ Y (pure bf16 1-product)
    gemm128_phase<false, 1><<<dim3(8, 32), 512, 0, stream>>>(
        Shi, nullptr, Ythi, nullptr, nullptr, Zhi, nullptr, n, d, n);

    // 5) out = relu(Z @ Wfe + B) (pure bf16 1-product)
    gemm128_phase<false, 2><<<dim3(8, 32), 512, 0, stream>>>(
        Zhi, nullptr, Wfeh, nullptr, Bb, out, nullptr, n, d, d);
}

// Round 12
// 288.159 us; speedup vs baseline: 1.0048x; 1.0048x over previous
//
#include <hip/hip_runtime.h>
#include <cstdint>

// ---------------------------------------------------------------------------
// out = relu((softmax((Y W^T)(Y W^T)^T) @ Y) @ (-0.5(Wf+Wf^T)) + B)
// n=4096, d=1024, fp32 in/out.
// R12 (= R11 resubmit; R11 hit container-failure, never ran):
// 2D XCD-chunked L2-aware block mapping (the only change vs R10, which
// passed). Each XCD owns a 4-row x 8-col tile rectangle, column-outer order:
// B-panel reused by 4 temporally-adjacent blocks, 4 A-panels (~4MB) stay
// L2-resident. Tests the L3-BW-bound theory for GEMM2/GEMM3.
// K-loops/fragments/epilogues verbatim from R10.
// ---------------------------------------------------------------------------

typedef __attribute__((ext_vector_type(8))) short short8;
typedef __attribute__((ext_vector_type(4))) short short4v;
typedef __attribute__((ext_vector_type(4))) float f32x4;

__device__ __forceinline__ short f2bf(float x) {            // RNE fp32 -> bf16
    unsigned u = __builtin_bit_cast(unsigned, x);
    u += 0x7fffu + ((u >> 16) & 1u);
    return (short)(u >> 16);
}
__device__ __forceinline__ float bf2f(short s) {
    unsigned u = ((unsigned)(unsigned short)s) << 16;
    return __builtin_bit_cast(float, u);
}

typedef const __attribute__((address_space(1))) void* gas1_t;
typedef __attribute__((address_space(3))) void* las3_t;
__device__ __forceinline__ void cp16(const void* g, void* l) {
    __builtin_amdgcn_global_load_lds((gas1_t)(uintptr_t)g, (las3_t)(uintptr_t)l, 16, 0, 0);
}

#define MFMA16(A, B, C) __builtin_amdgcn_mfma_f32_16x16x32_bf16(A, B, C, 0, 0, 0)

// 2D XCD-chunked mapping. 256-block grids only; 8 XCDs round-robin on lin%8.
// Rect per XCD = 4 rows x 8 cols, column-outer (idx: rows fastest).
// gx==16 (16x16 grid): rect grid 4x2.  gx==8 (8x32 grid): 8 row-bands.
__device__ __forceinline__ void xcd_map(int lin, int gx, int gy, int* prow, int* pcol) {
    const int nwg = gx * gy;
    if (nwg == 256 && (gx == 16 || gx == 8)) {
        const int xcd = lin & 7;
        const int idx = lin >> 3;            // 0..31
        const int r_loc = idx & 3;
        const int c_loc = idx >> 2;          // 0..7
        if (gx == 16) {
            const int rect_r = xcd & 3, rect_c = xcd >> 2;
            *prow = rect_r * 4 + r_loc;
            *pcol = rect_c * 8 + c_loc;
        } else {                             // gx == 8
            *prow = xcd * 4 + r_loc;
            *pcol = c_loc;
        }
    } else {                                 // fallback: R10's 1D chunking
        int sw = lin;
        if ((nwg & 7) == 0) { const int cpx = nwg >> 3; sw = (lin & 7) * cpx + (lin >> 3); }
        *prow = sw / gx;
        *pcol = sw % gx;
    }
}

// ---------------------------------------------------------------------------
// GEMM2: 256x256 tile, split-3 bf16. C[M,N] = (Ah+Al)[M,K] @ (Bh+Bl)^T.
// 512 thr / 8 waves (2Mx4N), wave tile 128x64, acc[8][4]. BK=32.
// LDS: 2 bufs x (Ah|Al|Bh|Bl planes of [256][32]sh) = 128 KB. 1 block/CU.
// ---------------------------------------------------------------------------
__global__ __launch_bounds__(512, 1)
void gemm256_split(const short* __restrict__ Ah, const short* __restrict__ Al,
                   const short* __restrict__ Bh, const short* __restrict__ Bl,
                   short* __restrict__ Ch, short* __restrict__ Cl,
                   int M, int N, int K)
{
    __shared__ short lds[2][32768];           // 128 KB

    const int tid  = threadIdx.x;
    const int lane = tid & 63;
    const int wave = tid >> 6;
    const int wr   = wave >> 2;               // 0..1  (128-row half)
    const int wc   = wave & 3;                // 0..3  (64-col quarter)

    int brow, bcol;
    xcd_map(blockIdx.y * gridDim.x + blockIdx.x, gridDim.x, gridDim.y, &brow, &bcol);
    const int bm = brow << 8;
    const int bn = bcol << 8;

    f32x4 acc[8][4];
#pragma unroll
    for (int m = 0; m < 8; ++m)
#pragma unroll
        for (int n = 0; n < 4; ++n)
#pragma unroll
            for (int q = 0; q < 4; ++q) acc[m][n][q] = 0.f;

    // staging: per plane-half (128 rows x 32), thread -> one 16B slot (R4 map)
    const int srow = tid >> 2;                               // 0..127
    const int csw  = (tid & 3) ^ ((tid >> 3) & 3);           // logical chunk
    const size_t oA = (size_t)(bm + srow) * K + csw * 8;
    const size_t oB = (size_t)(bn + srow) * K + csw * 8;
    const short* s0 = Ah + oA; const short* s1 = Al + oA;
    const short* s2 = Bh + oB; const short* s3 = Bl + oB;
    const size_t h128 = (size_t)128 * K;

    auto stage = [&](int t) {                  // 8 cp16 / thread / K-tile
        short* db = &lds[t & 1][0] + tid * 8;
        const int ko = t * 32;
        cp16(s0 + ko, db);          cp16(s0 + h128 + ko, db + 4096);
        cp16(s1 + ko, db + 8192);   cp16(s1 + h128 + ko, db + 12288);
        cp16(s2 + ko, db + 16384);  cp16(s2 + h128 + ko, db + 20480);
        cp16(s3 + ko, db + 24576);  cp16(s3 + h128 + ko, db + 28672);
    };

    // read-side (R3/R4-verified swizzle; row alignment mod 16 preserved)
    const int swz  = ((lane >> 4) ^ ((lane >> 1) & 3)) * 8;
    const int aoff = (wr * 128 + (lane & 15)) * 32 + swz;
    const int boff = (wc * 64  + (lane & 15)) * 32 + swz;

    const int nt = K >> 5;                    // 32 for K=1024
    stage(0);

    for (int t = 0; t < nt; ++t) {
        // stage(t) was issued one full tile (~8000 cyc) ago: vmcnt(0) is a
        // cheap certification; the barrier makes it collective.
        asm volatile("s_waitcnt vmcnt(0)" ::: "memory");
        __builtin_amdgcn_s_barrier();
        __builtin_amdgcn_sched_barrier(0);

        if (t + 1 < nt) stage(t + 1);          // other buffer: no read hazard

        const short* base = &lds[t & 1][0];
        short8 fbh[4], fbl[4];
#pragma unroll
        for (int n = 0; n < 4; ++n) {
            fbh[n] = *(const short8*)(base + 16384 + boff + n * 512);
            fbl[n] = *(const short8*)(base + 24576 + boff + n * 512);
        }
        __builtin_amdgcn_s_setprio(1);
#pragma unroll
        for (int m = 0; m < 8; ++m) {
            const short8 fah = *(const short8*)(base + aoff + m * 512);
            const short8 fal = *(const short8*)(base + 8192 + aoff + m * 512);
#pragma unroll
            for (int n = 0; n < 4; ++n) {
                acc[m][n] = MFMA16(fah, fbh[n], acc[m][n]);
                acc[m][n] = MFMA16(fah, fbl[n], acc[m][n]);
                acc[m][n] = MFMA16(fal, fbh[n], acc[m][n]);
            }
        }
        __builtin_amdgcn_s_setprio(0);
    }

    // epilogue: split write. C/D: col = lane&15, row = (lane>>4)*4 + q
    const int crow0 = bm + wr * 128 + ((lane >> 4) << 2);
    const int ccol0 = bn + wc * 64 + (lane & 15);
#pragma unroll
    for (int n = 0; n < 4; ++n) {
        const int c = ccol0 + n * 16;
#pragma unroll
        for (int m = 0; m < 8; ++m)
#pragma unroll
            for (int q = 0; q < 4; ++q) {
                const int r = crow0 + m * 16 + q;
                const float v = acc[m][n][q];
                const short hh = f2bf(v);
                Ch[(size_t)r * N + c] = hh;
                Cl[(size_t)r * N + c] = f2bf(v - bf2f(hh));
            }
    }
}

// ---------------------------------------------------------------------------
// 128x128 phase template (GEMM1/3/4) — loop verbatim from R8/R10 (passed).
// OUTMODE: 0 split bf16, 1 hi bf16, 2 f32+bias+relu.
// ---------------------------------------------------------------------------
template<bool SPLIT, int OUTMODE>
__global__ __launch_bounds__(512, 2)
void gemm128_phase(const short* __restrict__ Ah, const short* __restrict__ Al,
                   const short* __restrict__ Bh, const short* __restrict__ Bl,
                   const float* __restrict__ bias, void* Co_, void* Cl_,
                   int M, int N, int K)
{
    constexpr int BK = SPLIT ? 32 : 64;
    __shared__ short lds[2][16384];           // 64 KB

    const int tid  = threadIdx.x;
    const int lane = tid & 63;
    const int wave = tid >> 6;
    const int wr   = wave >> 2;               // 0..1
    const int wc   = wave & 3;                // 0..3

    int brow, bcol;
    xcd_map(blockIdx.y * gridDim.x + blockIdx.x, gridDim.x, gridDim.y, &brow, &bcol);
    const int bm = brow << 7;
    const int bn = bcol << 7;

    f32x4 acc[4][2];
#pragma unroll
    for (int m = 0; m < 4; ++m)
#pragma unroll
        for (int n = 0; n < 2; ++n)
#pragma unroll
            for (int q = 0; q < 4; ++q) acc[m][n][q] = 0.f;

    // staging sources: 4 cp16/thread/K-tile (R4-verified maps)
    const short *p0, *p1, *p2, *p3;
    if constexpr (SPLIT) {
        const int row = tid >> 2;                        // 0..127
        const int c4  = (tid & 3) ^ ((tid >> 3) & 3);
        const size_t oA = (size_t)(bm + row) * K + c4 * 8;
        const size_t oB = (size_t)(bn + row) * K + c4 * 8;
        p0 = Ah + oA; p1 = Al + oA; p2 = Bh + oB; p3 = Bl + oB;
    } else {
        const int row = tid >> 3;                        // 0..63
        const int lch = (tid & 7) ^ ((tid >> 3) & 7);
        const size_t oA = (size_t)(bm + row) * K + lch * 8;
        const size_t oB = (size_t)(bn + row) * K + lch * 8;
        p0 = Ah + oA; p1 = p0 + (size_t)64 * K;
        p2 = Bh + oB; p3 = p2 + (size_t)64 * K;
    }

    auto stage = [&](int t) {
        short* db = &lds[t & 1][0] + tid * 8;
        const int ko = t * BK;
        cp16(p0 + ko, db);
        cp16(p1 + ko, db + 4096);
        cp16(p2 + ko, db + 8192);
        cp16(p3 + ko, db + 12288);
    };

    int aoff, boff;
    if constexpr (SPLIT) {
        const int swz = ((lane >> 4) ^ ((lane >> 1) & 3)) * 8;
        aoff = (wr * 64 + (lane & 15)) * 32 + swz;
        boff = (wc * 32 + (lane & 15)) * 32 + swz;
    } else {
        aoff = (wr * 64 + (lane & 15)) * 64;
        boff = (wc * 32 + (lane & 15)) * 64;
    }

    const int nt = K / BK;
    stage(0); stage(1);

    for (int t = 0; t < nt; ++t) {
        if (t < nt - 1) { asm volatile("s_waitcnt vmcnt(4)" ::: "memory"); }
        else            { asm volatile("s_waitcnt vmcnt(0)" ::: "memory"); }
        __builtin_amdgcn_s_barrier();
        __builtin_amdgcn_sched_barrier(0);

        const short* base = &lds[t & 1][0];
        if constexpr (SPLIT) {
            short8 fah[4], fal[4], fbh[2], fbl[2];
#pragma unroll
            for (int n = 0; n < 2; ++n) {
                fbh[n] = *(const short8*)(base + 8192  + boff + n * 512);
                fbl[n] = *(const short8*)(base + 12288 + boff + n * 512);
            }
#pragma unroll
            for (int m = 0; m < 4; ++m) {
                fah[m] = *(const short8*)(base + aoff + m * 512);
                fal[m] = *(const short8*)(base + 4096 + aoff + m * 512);
            }
            __builtin_amdgcn_s_setprio(1);
#pragma unroll
            for (int m = 0; m < 2; ++m)
#pragma unroll
                for (int n = 0; n < 2; ++n) {
                    acc[m][n] = MFMA16(fah[m], fbh[n], acc[m][n]);
                    acc[m][n] = MFMA16(fah[m], fbl[n], acc[m][n]);
                    acc[m][n] = MFMA16(fal[m], fbh[n], acc[m][n]);
                }
            __builtin_amdgcn_s_setprio(0);
            asm volatile("s_waitcnt lgkmcnt(0)" ::: "memory");
            __builtin_amdgcn_sched_barrier(0);
            __builtin_amdgcn_s_barrier();
            __builtin_amdgcn_sched_barrier(0);
            if (t + 2 < nt) stage(t + 2);
            __builtin_amdgcn_s_setprio(1);
#pragma unroll
            for (int m = 2; m < 4; ++m)
#pragma unroll
                for (int n = 0; n < 2; ++n) {
                    acc[m][n] = MFMA16(fah[m], fbh[n], acc[m][n]);
                    acc[m][n] = MFMA16(fah[m], fbl[n], acc[m][n]);
                    acc[m][n] = MFMA16(fal[m], fbh[n], acc[m][n]);
                }
            __builtin_amdgcn_s_setprio(0);
        } else {
            short8 fa[2][4], fb[2][2];
#pragma unroll
            for (int ks = 0; ks < 2; ++ks) {
                const int sw = ((ks * 4 + (lane >> 4)) ^ (lane & 7)) * 8;
#pragma unroll
                for (int m = 0; m < 4; ++m)
                    fa[ks][m] = *(const short8*)(base + aoff + sw + m * 1024);
#pragma unroll
                for (int n = 0; n < 2; ++n)
                    fb[ks][n] = *(const short8*)(base + 8192 + boff + sw + n * 1024);
            }
            __builtin_amdgcn_s_setprio(1);
#pragma unroll
            for (int m = 0; m < 4; ++m)
#pragma unroll
                for (int n = 0; n < 2; ++n)
                    acc[m][n] = MFMA16(fa[0][m], fb[0][n], acc[m][n]);
            __builtin_amdgcn_s_setprio(0);
            asm volatile("s_waitcnt lgkmcnt(0)" ::: "memory");
            __builtin_amdgcn_sched_barrier(0);
            __builtin_amdgcn_s_barrier();
            __builtin_amdgcn_sched_barrier(0);
            if (t + 2 < nt) stage(t + 2);
            __builtin_amdgcn_s_setprio(1);
#pragma unroll
            for (int m = 0; m < 4; ++m)
#pragma unroll
                for (int n = 0; n < 2; ++n)
                    acc[m][n] = MFMA16(fa[1][m], fb[1][n], acc[m][n]);
            __builtin_amdgcn_s_setprio(0);
        }
    }

    // epilogue: C/D layout col = lane&15, row = (lane>>4)*4 + q
    const int crow0 = bm + wr * 64 + ((lane >> 4) << 2);
    const int ccol0 = bn + wc * 32 + (lane & 15);
    if constexpr (OUTMODE == 2) {
        float* C = (float*)Co_;
#pragma unroll
        for (int n = 0; n < 2; ++n) {
            const int c = ccol0 + n * 16;
            const float bv = bias[c];
#pragma unroll
            for (int m = 0; m < 4; ++m)
#pragma unroll
                for (int q = 0; q < 4; ++q) {
                    const int r = crow0 + m * 16 + q;
                    C[(size_t)r * N + c] = fmaxf(acc[m][n][q] + bv, 0.f);
                }
        }
    } else if constexpr (OUTMODE == 1) {
        short* Ch = (short*)Co_;
#pragma unroll
        for (int n = 0; n < 2; ++n) {
            const int c = ccol0 + n * 16;
#pragma unroll
            for (int m = 0; m < 4; ++m)
#pragma unroll
                for (int q = 0; q < 4; ++q) {
                    const int r = crow0 + m * 16 + q;
                    Ch[(size_t)r * N + c] = f2bf(acc[m][n][q]);
                }
        }
    } else {
        short* Ch = (short*)Co_;
        short* Cl = (short*)Cl_;
#pragma unroll
        for (int n = 0; n < 2; ++n) {
            const int c = ccol0 + n * 16;
#pragma unroll
            for (int m = 0; m < 4; ++m)
#pragma unroll
                for (int q = 0; q < 4; ++q) {
                    const int r = crow0 + m * 16 + q;
                    const float v = acc[m][n][q];
                    const short hh = f2bf(v);
                    Ch[(size_t)r * N + c] = hh;
                    Cl[(size_t)r * N + c] = f2bf(v - bf2f(hh));
                }
        }
    }
}

// ---------------------------------------------------------------------------
// Row softmax over split logits; writes PROBABILITIES as hi-bf16 into Shi.
// ---------------------------------------------------------------------------
__global__ __launch_bounds__(256)
void softmax_hi(short* __restrict__ Shi, const short* __restrict__ Slo)
{
    const int row = blockIdx.x;
    short8* ph = (short8*)(Shi + (size_t)row * 4096);
    const short8* pl = (const short8*)(Slo + (size_t)row * 4096);
    const int t = threadIdx.x;

    short8 h0 = ph[t], h1 = ph[t + 256];
    short8 l0 = pl[t], l1 = pl[t + 256];
    float x[16];
#pragma unroll
    for (int j = 0; j < 8; ++j) {
        x[j]     = bf2f(h0[j]) + bf2f(l0[j]);
        x[8 + j] = bf2f(h1[j]) + bf2f(l1[j]);
    }
    float mx = x[0];
#pragma unroll
    for (int j = 1; j < 16; ++j) mx = fmaxf(mx, x[j]);
#pragma unroll
    for (int off = 32; off > 0; off >>= 1) mx = fmaxf(mx, __shfl_xor(mx, off));

    __shared__ float rm[4], rs[4];
    const int wv = t >> 6, ln = t & 63;
    if (ln == 0) rm[wv] = mx;
    __syncthreads();
    mx = fmaxf(fmaxf(rm[0], rm[1]), fmaxf(rm[2], rm[3]));

    float s = 0.f;
#pragma unroll
    for (int j = 0; j < 16; ++j) { x[j] = __expf(x[j] - mx); s += x[j]; }
#pragma unroll
    for (int off = 32; off > 0; off >>= 1) s += __shfl_xor(s, off);
    if (ln == 0) rs[wv] = s;
    __syncthreads();
    s = rs[0] + rs[1] + rs[2] + rs[3];

    const float inv = 1.f / s;
    short8 o0, o1;
#pragma unroll
    for (int j = 0; j < 8; ++j) {
        o0[j] = f2bf(x[j] * inv);
        o1[j] = f2bf(x[8 + j] * inv);
    }
    ph[t] = o0; ph[t + 256] = o1;
}

// ---------------------------------------------------------------------------
// Y (4096x1024 f32) -> Yhi/Ylo (row-major split) + Ythi (transposed hi bf16)
// ---------------------------------------------------------------------------
__global__ __launch_bounds__(256)
void split_y(const float* __restrict__ Y, short* __restrict__ Yhi,
             short* __restrict__ Ylo, short* __restrict__ Yt)
{
    __shared__ float tb[64][65];
    const int rb = blockIdx.y * 64, cb = blockIdx.x * 64;
    const int t = threadIdx.x;
    const int r = t >> 4, c4 = (t & 15) * 4;
#pragma unroll
    for (int it = 0; it < 4; ++it) {
        const int row = rb + r + it * 16;
        const float4 v = *(const float4*)&Y[(size_t)row * 1024 + cb + c4];
        const float f[4] = {v.x, v.y, v.z, v.w};
        short4v h, l;
#pragma unroll
        for (int k = 0; k < 4; ++k) {
            const short hh = f2bf(f[k]);
            h[k] = hh;
            l[k] = f2bf(f[k] - bf2f(hh));
        }
        *(short4v*)&Yhi[(size_t)row * 1024 + cb + c4] = h;
        *(short4v*)&Ylo[(size_t)row * 1024 + cb + c4] = l;
        tb[r + it * 16][c4 + 0] = v.x; tb[r + it * 16][c4 + 1] = v.y;
        tb[r + it * 16][c4 + 2] = v.z; tb[r + it * 16][c4 + 3] = v.w;
    }
    __syncthreads();
    const int orow = t >> 2, oc0 = (t & 3) * 16;
    short8 h8[2];
#pragma unroll
    for (int g = 0; g < 2; ++g)
#pragma unroll
        for (int j = 0; j < 8; ++j)
            h8[g][j] = f2bf(tb[oc0 + g * 8 + j][orow]);
    const size_t ob = (size_t)(cb + orow) * 4096 + rb + oc0;
    *(short8*)&Yt[ob] = h8[0];
    *(short8*)&Yt[ob + 8] = h8[1];
}

// W (1024x1024 f32) -> Whi/Wlo
__global__ __launch_bounds__(256)
void split_w(const float* __restrict__ Wm, short* __restrict__ Wh, short* __restrict__ Wl)
{
    const size_t idx = ((size_t)blockIdx.x * 256 + threadIdx.x) * 4;
    const float4 v = *(const float4*)&Wm[idx];
    const float f[4] = {v.x, v.y, v.z, v.w};
    short4v h, l;
#pragma unroll
    for (int k = 0; k < 4; ++k) {
        const short hh = f2bf(f[k]);
        h[k] = hh;
        l[k] = f2bf(f[k] - bf2f(hh));
    }
    *(short4v*)&Wh[idx] = h;
    *(short4v*)&Wl[idx] = l;
}

// Wfeh = bf16(-0.5*(Wf + Wf^T))
__global__ __launch_bounds__(256)
void symm_hi(const float* __restrict__ Wf, short* __restrict__ Fh)
{
    const int i  = blockIdx.x;
    const int j0 = threadIdx.x * 4;
    const float4 rv = *(const float4*)&Wf[(size_t)i * 1024 + j0];
    const float c0 = Wf[(size_t)(j0 + 0) * 1024 + i];
    const float c1 = Wf[(size_t)(j0 + 1) * 1024 + i];
    const float c2 = Wf[(size_t)(j0 + 2) * 1024 + i];
    const float c3 = Wf[(size_t)(j0 + 3) * 1024 + i];
    short4v h;
    h[0] = f2bf(-0.5f * (rv.x + c0));
    h[1] = f2bf(-0.5f * (rv.y + c1));
    h[2] = f2bf(-0.5f * (rv.z + c2));
    h[3] = f2bf(-0.5f * (rv.w + c3));
    *(short4v*)&Fh[(size_t)i * 1024 + j0] = h;
}

// ---------------------------------------------------------------------------
extern "C" void kernel_launch(void* const* d_in, const int* in_sizes, int n_in,
                              void* d_out, int out_size, void* d_ws, size_t ws_size,
                              hipStream_t stream)
{
    const float* Y  = (const float*)d_in[0];   // (4096, 1024)
    const float* W  = (const float*)d_in[1];   // (1024, 1024)
    const float* Wf = (const float*)d_in[2];   // (1024, 1024)
    const float* Bb = (const float*)d_in[3];   // (1, 1024)
    float* out = (float*)d_out;

    const int n = 4096, d = 1024;

    // ws layout, 94.4 MB (same as R3-R10):
    char* w = (char*)d_ws;
    short* Ythi = (short*)w; w += (size_t)d * n * 2;   //  8.39 MB
    short* Wfeh = (short*)w; w += (size_t)d * d * 2;   //  2.10 MB
    short* YWth = (short*)w; w += (size_t)n * d * 2;   //  8.39 MB (reused as Zhi)
    short* YWtl = (short*)w; w += (size_t)n * d * 2;   //  8.39 MB
    short* Shi  = (short*)w; w += (size_t)n * n * 2;   // 33.55 MB
    short* Slo  = (short*)w; w += (size_t)n * n * 2;   // 33.55 MB
    // transient split inputs aliased into Shi region (dead before S written):
    short* Yhi = Shi;
    short* Ylo = Yhi + (size_t)n * d;
    short* Whi = Ylo + (size_t)n * d;
    short* Wlo = Whi + (size_t)d * d;
    short* Zhi = YWth;                                  // YWt dead after GEMM2

    split_y<<<dim3(16, 64), 256, 0, stream>>>(Y, Yhi, Ylo, Ythi);
    split_w<<<dim3(1024), 256, 0, stream>>>(W, Whi, Wlo);
    symm_hi<<<dim3(1024), 256, 0, stream>>>(Wf, Wfeh);

    // 1) YWt = Y @ W^T (split 3-product, 128^2 phase template)
    gemm128_phase<true, 0><<<dim3(8, 32), 512, 0, stream>>>(
        Yhi, Ylo, Whi, Wlo, nullptr, YWth, YWtl, n, d, d);

    // 2) S = YWt @ YWt^T (split 3-product, 256^2 full grid, single-barrier)
    gemm256_split<<<dim3(16, 16), 512, 0, stream>>>(
        YWth, YWtl, YWth, YWtl, Shi, Slo, n, n, d);

    // 3) A = softmax(S): probabilities as hi-bf16 into Shi
    softmax_hi<<<dim3(n), 256, 0, stream>>>(Shi, Slo);

    // 4) Z = A @ Y (pure bf16 1-product)
    gemm128_phase<false, 1><<<dim3(8, 32), 512, 0, stream>>>(
        Shi, nullptr, Ythi, nullptr, nullptr, Zhi, nullptr, n, d, n);

    // 5) out = relu(Z @ Wfe + B) (pure bf16 1-product)
    gemm128_phase<false, 2><<<dim3(8, 32), 512, 0, stream>>>(
        Zhi, nullptr, Wfeh, nullptr, Bb, out, nullptr, n, d, d);
}